// Round 9
// baseline (250.397 us; speedup 1.0000x reference)
//
#include <hip/hip_runtime.h>

// N=4096, D=1024 self-attention, all GEMMs NT-form bf16 MFMA, fp32 acc.
// R4: BK=64.  R5: XCD-locality block swizzle.  R6: k_pv BK=128.
// R7: softmax fused into k_score (exp + rowsum atomics) / k_pv (1/rowsum).
// R8: 32x32x16 MFMA -- regressed on 4-way LDS conflicts (32 lanes, 8 chunk
//     positions/row, 128B row stride = bank wrap).
// R9: q-pair-major LDS layout: chunk (r,q) at 16B-unit (q>>1)*2*ROWS + r*2 +
//     (q&1). MFMA-step reads = contiguous 1KB per wave -> conflict-free by
//     construction. Staging = 32 rows x 32B segments per gld_lds16 pass.
//   A/B frag: [m=lane&31][k=(lane>>5)*8+j]; C/D: col=lane&31,
//   row=(reg&3)+8*(reg>>2)+4*(lane>>5)  (both verified by R8 correctness).
//
// ws layout (64 MB):
//   Qb bf16[4096,1024] @ 0      Kb @ 8MB     Vb @ 16MB    Vt bf16[1024,4096] @ 24MB
//   SP bf16[4096,4096] @ 32MB   (exp'd scores)
//   xb @ 32MB (overlaps SP; dead before k_score), Wqb @ 40MB, Wkb @ 42MB, Wvb @ 44MB
//   rowsum fp32[4096] @ 16MB (over dead Vb; memset after transpose)

#define N_TOK 4096
#define DDIM  1024

typedef short s16x8  __attribute__((ext_vector_type(8)));
typedef float f32x16 __attribute__((ext_vector_type(16)));

__device__ inline short f2b(float f) {
  unsigned int u = __float_as_uint(f);
  unsigned int r = (u + 0x7FFFu + ((u >> 16) & 1u)) >> 16;
  return (short)(unsigned short)r;
}

__device__ __forceinline__ void gld_lds16(const short* g, short* l) {
  __builtin_amdgcn_global_load_lds(
      (const __attribute__((address_space(1))) unsigned int*)g,
      (__attribute__((address_space(3))) unsigned int*)l, 16, 0, 0);
}

// XCD-locality remap for grids with GY=32: XCD (L%8) gets a 4-row-tile band.
__device__ __forceinline__ void xcd_remap(int gx, int& bx, int& by) {
  const int L = by * gx + bx;
  const int g = L & 7, h = L >> 3;
  by = g * 4 + (h & 3);
  bx = h >> 2;
}

// ---------------------------------------------------------------------------
// Core NT GEMM tile, bf16 in, fp32 acc, 32x32x16 MFMA. MODE epilogues:
//   0: bf16 store of scale*acc + bias        (aux = bias)
//   1: bf16 store of exp(scale*acc) + atomicAdd row sums (aux = rowsum)
//   2: fp32 store of acc / rowsum[row]       (aux = rowsum)
// LDS: q-pair-major. 16B-unit index of chunk (r,q): (q>>1)*2*ROWS + r*2 + (q&1).
// 256 threads = 4 waves in 2x2; wave tile (BM/2)x(BN/2) as TIxTJ 32x32 MFMAs.
// ---------------------------------------------------------------------------
template<int BM, int BN, int BK, int MODE>
__device__ __forceinline__ void gemm_core(
    const short* __restrict__ A, const short* __restrict__ B,
    void* __restrict__ C, float* __restrict__ aux,
    int K, int ld, int ldc, float scale, int row0, int col0)
{
  constexpr int WM = BM / 2, WN = BN / 2, TI = WM / 32, TJ = WN / 32;
  constexpr int CPR = BK / 8;          // 16B chunks per row
  constexpr int CA = BM * CPR / 256;   // staging chunks per thread
  constexpr int CB = BN * CPR / 256;
  constexpr int KS = BK / 16;          // MFMA K-steps per iter
  __shared__ short As[BM * BK];
  __shared__ short Bs[BN * BK];

  const int tid  = threadIdx.x;
  const int wave = tid >> 6, lane = tid & 63;
  const int wm = wave >> 1, wn = wave & 1;
  const int l31 = lane & 31, h5 = lane >> 5;

  f32x16 acc[TI][TJ];
  #pragma unroll
  for (int i = 0; i < TI; i++)
    #pragma unroll
    for (int j = 0; j < TJ; j++)
      #pragma unroll
      for (int e = 0; e < 16; e++) acc[i][j][e] = 0.f;

  for (int kk = 0; kk < K; kk += BK) {
    __syncthreads();
    // A: unit id -> ks = id/(2*BM), r = (id%(2*BM))>>1, q = ks*2 + (id&1)
    #pragma unroll
    for (int c = 0; c < CA; c++) {
      const int id = c * 256 + wave * 64 + lane;
      const int ks = id / (2 * BM);
      const int rem = id - ks * (2 * BM);
      const int r = rem >> 1, qh = rem & 1;
      gld_lds16(A + (size_t)(row0 + r) * ld + kk + (ks * 2 + qh) * 8,
                &As[(c * 256 + wave * 64) * 8]);
    }
    #pragma unroll
    for (int c = 0; c < CB; c++) {
      const int id = c * 256 + wave * 64 + lane;
      const int ks = id / (2 * BN);
      const int rem = id - ks * (2 * BN);
      const int r = rem >> 1, qh = rem & 1;
      gld_lds16(B + (size_t)(col0 + r) * ld + kk + (ks * 2 + qh) * 8,
                &Bs[(c * 256 + wave * 64) * 8]);
    }
    __syncthreads();

    #pragma unroll
    for (int ks = 0; ks < KS; ks++) {
      s16x8 af[TI], bf[TJ];
      #pragma unroll
      for (int i = 0; i < TI; i++) {
        const int row = wm * WM + i * 32 + l31;
        af[i] = *reinterpret_cast<const s16x8*>(
            &As[(ks * 2 * BM + row * 2 + h5) * 8]);
      }
      #pragma unroll
      for (int j = 0; j < TJ; j++) {
        const int row = wn * WN + j * 32 + l31;
        bf[j] = *reinterpret_cast<const s16x8*>(
            &Bs[(ks * 2 * BN + row * 2 + h5) * 8]);
      }
      #pragma unroll
      for (int i = 0; i < TI; i++)
        #pragma unroll
        for (int j = 0; j < TJ; j++)
          acc[i][j] = __builtin_amdgcn_mfma_f32_32x32x16_bf16(af[i], bf[j], acc[i][j], 0, 0, 0);
    }
  }

  // C/D row within a 32x32 tile for register reg: (reg&3) + 8*(reg>>2) + 4*h5
  if constexpr (MODE == 0) {
    #pragma unroll
    for (int j = 0; j < TJ; j++) {
      const int c = col0 + wn * WN + j * 32 + l31;
      const float bb = aux[c];
      #pragma unroll
      for (int i = 0; i < TI; i++) {
        const int r0 = row0 + wm * WM + i * 32 + 4 * h5;
        #pragma unroll
        for (int reg = 0; reg < 16; reg++) {
          const int row = r0 + (reg & 3) + 8 * (reg >> 2);
          ((short*)C)[(size_t)row * ldc + c] = f2b(acc[i][j][reg] * scale + bb);
        }
      }
    }
  } else if constexpr (MODE == 1) {
    #pragma unroll
    for (int i = 0; i < TI; i++) {
      const int r0 = row0 + wm * WM + i * 32 + 4 * h5;
      float ex[TJ][16];
      #pragma unroll
      for (int j = 0; j < TJ; j++) {
        const int c = col0 + wn * WN + j * 32 + l31;
        #pragma unroll
        for (int reg = 0; reg < 16; reg++) {
          const int row = r0 + (reg & 3) + 8 * (reg >> 2);
          ex[j][reg] = __expf(acc[i][j][reg] * scale);
          ((short*)C)[(size_t)row * ldc + c] = f2b(ex[j][reg]);
        }
      }
      #pragma unroll
      for (int reg = 0; reg < 16; reg++) {
        float s = 0.f;
        #pragma unroll
        for (int j = 0; j < TJ; j++) s += ex[j][reg];
        s += __shfl_xor(s, 1, 64);
        s += __shfl_xor(s, 2, 64);
        s += __shfl_xor(s, 4, 64);
        s += __shfl_xor(s, 8, 64);
        s += __shfl_xor(s, 16, 64);   // stays within 32-lane half (same row)
        if (l31 == 0) {
          const int row = r0 + (reg & 3) + 8 * (reg >> 2);
          atomicAdd(&aux[row], s);
        }
      }
    }
  } else {
    #pragma unroll
    for (int i = 0; i < TI; i++) {
      const int r0 = row0 + wm * WM + i * 32 + 4 * h5;
      float linv[16];
      #pragma unroll
      for (int reg = 0; reg < 16; reg++)
        linv[reg] = 1.0f / aux[r0 + (reg & 3) + 8 * (reg >> 2)];
      #pragma unroll
      for (int j = 0; j < TJ; j++) {
        const int c = col0 + wn * WN + j * 32 + l31;
        #pragma unroll
        for (int reg = 0; reg < 16; reg++) {
          const int row = r0 + (reg & 3) + 8 * (reg >> 2);
          ((float*)C)[(size_t)row * ldc + c] = acc[i][j][reg] * linv[reg];
        }
      }
    }
  }
}

// ---------------------------------------------------------------------------
// fp32 -> bf16 conversion for x, Wq, Wk, Wv (one launch). Unit = 8 floats.
// ---------------------------------------------------------------------------
#define XU  (N_TOK * DDIM / 8)      // 524288
#define WU  (DDIM * DDIM / 8)       // 131072
__global__ __launch_bounds__(256)
void cvt_all(const float* __restrict__ x,  const float* __restrict__ wq,
             const float* __restrict__ wk, const float* __restrict__ wv,
             short* __restrict__ xb, short* __restrict__ wqb,
             short* __restrict__ wkb, short* __restrict__ wvb)
{
  int gid = blockIdx.x * 256 + threadIdx.x;
  const float* src; short* dst; int off;
  if (gid < XU)               { src = x;  dst = xb;  off = gid; }
  else if (gid < XU + WU)     { src = wq; dst = wqb; off = gid - XU; }
  else if (gid < XU + 2 * WU) { src = wk; dst = wkb; off = gid - XU - WU; }
  else                        { src = wv; dst = wvb; off = gid - XU - 2 * WU; }
  const float4* g = reinterpret_cast<const float4*>(src) + (size_t)off * 2;
  float4 a = g[0], b = g[1];
  s16x8 o;
  o[0] = f2b(a.x); o[1] = f2b(a.y); o[2] = f2b(a.z); o[3] = f2b(a.w);
  o[4] = f2b(b.x); o[5] = f2b(b.y); o[6] = f2b(b.z); o[7] = f2b(b.w);
  reinterpret_cast<s16x8*>(dst)[off] = o;
}

// ---------------------------------------------------------------------------
// GEMM kernels (all with XCD-locality remap; GY must be 32)
// ---------------------------------------------------------------------------
__global__ __launch_bounds__(256)
void k_qkv(const short* __restrict__ xb,
           const short* __restrict__ Wqb, const short* __restrict__ Wkb,
           const short* __restrict__ Wvb,
           const float* __restrict__ bq, const float* __restrict__ bk,
           const float* __restrict__ bv,
           short* __restrict__ Qb, short* __restrict__ Kb, short* __restrict__ Vb)
{
  const short* W; const float* bias; short* out;
  if (blockIdx.z == 0)      { W = Wqb; bias = bq; out = Qb; }
  else if (blockIdx.z == 1) { W = Wkb; bias = bk; out = Kb; }
  else                      { W = Wvb; bias = bv; out = Vb; }
  int bx = blockIdx.x, by = blockIdx.y;
  xcd_remap(DDIM / 128, bx, by);
  gemm_core<128, 128, 64, 0>(xb, W, out, (float*)bias, DDIM, DDIM, DDIM, 1.0f,
                             by * 128, bx * 128);
}

__global__ __launch_bounds__(256)
void k_score(const short* __restrict__ Qb, const short* __restrict__ Kb,
             short* __restrict__ SP, float* __restrict__ rowsum)
{
  int bx = blockIdx.x, by = blockIdx.y;
  xcd_remap(N_TOK / 128, bx, by);
  gemm_core<128, 128, 64, 1>(Qb, Kb, SP, rowsum, DDIM, DDIM, N_TOK,
                             0.03125f, by * 128, bx * 128);
}

__global__ __launch_bounds__(256)
void k_pv(const short* __restrict__ SP, const short* __restrict__ Vt,
          float* __restrict__ out, const float* __restrict__ rowsum)
{
  int bx = blockIdx.x, by = blockIdx.y;
  xcd_remap(DDIM / 64, bx, by);
  gemm_core<128, 64, 128, 2>(SP, Vt, out, (float*)rowsum, N_TOK, N_TOK, DDIM,
                             1.0f, by * 128, bx * 64);
}

// ---------------------------------------------------------------------------
// V [4096,1024] -> Vt [1024,4096] (bf16)
// ---------------------------------------------------------------------------
__global__ __launch_bounds__(256)
void transpose_bf16(const short* __restrict__ in, short* __restrict__ out)
{
  __shared__ short t[64][65];
  const int j0 = blockIdx.x * 64;
  const int i0 = blockIdx.y * 64;
  const int tid = threadIdx.x;
  const int r = tid >> 2;
  const int c = (tid & 3) * 16;

  const s16x8* g = reinterpret_cast<const s16x8*>(in + (size_t)(i0 + r) * DDIM + j0 + c);
  s16x8 v0 = g[0], v1 = g[1];
  #pragma unroll
  for (int k = 0; k < 8; k++) { t[r][c + k] = v0[k]; t[r][c + 8 + k] = v1[k]; }
  __syncthreads();

  s16x8 w0, w1;
  #pragma unroll
  for (int k = 0; k < 8; k++) { w0[k] = t[c + k][r]; w1[k] = t[c + 8 + k][r]; }
  s16x8* go = reinterpret_cast<s16x8*>(out + (size_t)(j0 + r) * N_TOK + i0 + c);
  go[0] = w0; go[1] = w1;
}

// ---------------------------------------------------------------------------
extern "C" void kernel_launch(void* const* d_in, const int* in_sizes, int n_in,
                              void* d_out, int out_size, void* d_ws, size_t ws_size,
                              hipStream_t stream)
{
  const float* x  = (const float*)d_in[0];
  const float* Wq = (const float*)d_in[1];
  const float* bq = (const float*)d_in[2];
  const float* Wk = (const float*)d_in[3];
  const float* bk = (const float*)d_in[4];
  const float* Wv = (const float*)d_in[5];
  const float* bv = (const float*)d_in[6];
  float* out = (float*)d_out;

  char* ws = (char*)d_ws;
  const size_t MB = 1024 * 1024;
  short* Qb  = (short*)(ws + 0 * MB);
  short* Kb  = (short*)(ws + 8 * MB);
  short* Vb  = (short*)(ws + 16 * MB);
  short* Vt  = (short*)(ws + 24 * MB);
  short* SP  = (short*)(ws + 32 * MB);   // 32 MB, live from k_score onward
  short* xb  = (short*)(ws + 32 * MB);   // overlaps SP (dead before k_score)
  short* Wqb = (short*)(ws + 40 * MB);
  short* Wkb = (short*)(ws + 42 * MB);
  short* Wvb = (short*)(ws + 44 * MB);
  float* rowsum = (float*)(ws + 16 * MB); // over dead Vb (memset after transpose)

  dim3 b256(256);

  // fp32 -> bf16 for x and the three W's
  cvt_all<<<dim3((XU + 3 * WU) / 256), b256, 0, stream>>>(
      x, Wq, Wk, Wv, xb, Wqb, Wkb, Wvb);

  // Q/K/V = x @ W^T + b   (bf16 out), batched over z
  k_qkv<<<dim3(DDIM / 128, N_TOK / 128, 3), b256, 0, stream>>>(
      xb, Wqb, Wkb, Wvb, bq, bk, bv, Qb, Kb, Vb);

  // Vt = V^T
  transpose_bf16<<<dim3(DDIM / 64, N_TOK / 64), b256, 0, stream>>>(Vb, Vt);

  // zero row-sum accumulator (Vb now dead)
  hipMemsetAsync(rowsum, 0, N_TOK * sizeof(float), stream);

  // P = exp(Q @ K^T / 32) (bf16) + rowsum atomics
  k_score<<<dim3(N_TOK / 128, N_TOK / 128), b256, 0, stream>>>(Qb, Kb, SP, rowsum);

  // O = (P @ Vt^T) / rowsum  (fp32 out), 128x64 tiles, BK=128
  k_pv<<<dim3(DDIM / 64, N_TOK / 128), b256, 0, stream>>>(SP, Vt, out, rowsum);
}

// Round 11
// 222.348 us; speedup vs baseline: 1.1262x; 1.1262x over previous
//
#include <hip/hip_runtime.h>

// N=4096, D=1024 self-attention, all GEMMs NT-form bf16 MFMA (16x16x32), fp32 acc.
// R4: BK=64 + XOR swizzle (slot = q ^ (r&MASK)) -> 0 bank conflicts (verified).
// R5: XCD-locality block swizzle (k_pv FETCH 135->49MB).
// R6: k_pv BK=128 (fewer barrier drains at fixed 2 blocks/CU).
// R7: softmax fused: k_score does exp + rowsum atomics, k_pv divides by rowsum.
// R8/R9: 32x32x16 MFMA attempts -- identical 4.19M LDS conflicts both ways -> REVERTED.
// R10: folded rowsum zeroing into cvt_all but placed rowsum INSIDE SP -> NaN.
// R11: rowsum @ ws+64MB. ws_size >= 112MB is proven by R3's counter evidence
//   (split-4 path ran: one k_pv_split dispatch wrote 64MB of partials), so
//   ws+64MB is allocated and untouched by all kernels. Everything else = R7.
//
// ws layout:
//   Qb bf16[4096,1024] @ 0      Kb @ 8MB     Vb @ 16MB    Vt bf16[1024,4096] @ 24MB
//   SP bf16[4096,4096] @ 32MB   (exp'd scores; spans 32..64MB!)
//   xb @ 32MB (overlaps SP; dead before k_score), Wqb @ 40MB, Wkb @ 42MB, Wvb @ 44MB
//   rowsum fp32[4096] @ 64MB    (past SP; zeroed by cvt_all, written only by k_score)

#define N_TOK 4096
#define DDIM  1024

typedef short s16x8 __attribute__((ext_vector_type(8)));
typedef float f32x4 __attribute__((ext_vector_type(4)));

__device__ inline short f2b(float f) {
  unsigned int u = __float_as_uint(f);
  unsigned int r = (u + 0x7FFFu + ((u >> 16) & 1u)) >> 16;
  return (short)(unsigned short)r;
}

__device__ __forceinline__ void gld_lds16(const short* g, short* l) {
  __builtin_amdgcn_global_load_lds(
      (const __attribute__((address_space(1))) unsigned int*)g,
      (__attribute__((address_space(3))) unsigned int*)l, 16, 0, 0);
}

// XCD-locality remap for grids with GY=32: XCD (L%8) gets a 4-row-tile band.
__device__ __forceinline__ void xcd_remap(int gx, int& bx, int& by) {
  const int L = by * gx + bx;
  const int g = L & 7, h = L >> 3;
  by = g * 4 + (h & 3);
  bx = h >> 2;
}

// ---------------------------------------------------------------------------
// Core NT GEMM tile, bf16 in, fp32 acc, 16x16x32 MFMA. MODE epilogues:
//   0: bf16 store of scale*acc + bias        (aux = bias)
//   1: bf16 store of exp(scale*acc) + atomicAdd row sums (aux = rowsum)
//   2: fp32 store of acc / rowsum[row]       (aux = rowsum)
// LDS chunk q of row r at slot q ^ (r & (BK/8-1)) -> conflict-free b128 reads
// (verified 0 SQ_LDS_BANK_CONFLICT in R4-R7).
// 256 threads = 4 waves in 2x2; wave tile (BM/2)x(BN/2) as 16x16 MFMAs.
// ---------------------------------------------------------------------------
template<int BM, int BN, int BK, int MODE>
__device__ __forceinline__ void gemm_core(
    const short* __restrict__ A, const short* __restrict__ B,
    void* __restrict__ C, float* __restrict__ aux,
    int K, int ld, int ldc, float scale, int row0, int col0)
{
  constexpr int WM = BM / 2, WN = BN / 2, AI = WM / 16, AJ = WN / 16;
  constexpr int CPR = BK / 8;
  constexpr int MASK = CPR - 1;
  constexpr int CA = BM * CPR / 256;
  constexpr int CB = BN * CPR / 256;
  constexpr int NH = BK / 32;
  __shared__ short As[BM * BK];
  __shared__ short Bs[BN * BK];

  const int tid  = threadIdx.x;
  const int wave = tid >> 6, lane = tid & 63;
  const int wm = wave >> 1, wn = wave & 1;
  const int quad = lane >> 4, lr = lane & 15;

  f32x4 acc[AI][AJ];
  #pragma unroll
  for (int i = 0; i < AI; i++)
    #pragma unroll
    for (int j = 0; j < AJ; j++) acc[i][j] = {0.f, 0.f, 0.f, 0.f};

  for (int kk = 0; kk < K; kk += BK) {
    __syncthreads();
    #pragma unroll
    for (int c = 0; c < CA; c++) {
      const int id = c * 256 + wave * 64 + lane;
      const int r = id / CPR, slot = id & MASK;
      const int q = slot ^ (r & MASK);
      gld_lds16(A + (size_t)(row0 + r) * ld + kk + q * 8,
                &As[(c * 256 + wave * 64) * 8]);
    }
    #pragma unroll
    for (int c = 0; c < CB; c++) {
      const int id = c * 256 + wave * 64 + lane;
      const int r = id / CPR, slot = id & MASK;
      const int q = slot ^ (r & MASK);
      gld_lds16(B + (size_t)(col0 + r) * ld + kk + q * 8,
                &Bs[(c * 256 + wave * 64) * 8]);
    }
    __syncthreads();

    #pragma unroll
    for (int h = 0; h < NH; h++) {
      s16x8 af[AI], bf[AJ];
      #pragma unroll
      for (int i = 0; i < AI; i++) {
        const int row = wm * WM + i * 16 + lr;
        const int ch = (h * 4 + quad) ^ (row & MASK);
        af[i] = *reinterpret_cast<const s16x8*>(&As[(row * CPR + ch) * 8]);
      }
      #pragma unroll
      for (int j = 0; j < AJ; j++) {
        const int row = wn * WN + j * 16 + lr;
        const int ch = (h * 4 + quad) ^ (row & MASK);
        bf[j] = *reinterpret_cast<const s16x8*>(&Bs[(row * CPR + ch) * 8]);
      }
      #pragma unroll
      for (int i = 0; i < AI; i++)
        #pragma unroll
        for (int j = 0; j < AJ; j++)
          acc[i][j] = __builtin_amdgcn_mfma_f32_16x16x32_bf16(af[i], bf[j], acc[i][j], 0, 0, 0);
    }
  }

  if constexpr (MODE == 0) {
    float bb[AJ];
    #pragma unroll
    for (int j = 0; j < AJ; j++) bb[j] = aux[col0 + wn * WN + j * 16 + lr];
    #pragma unroll
    for (int i = 0; i < AI; i++) {
      const int r0 = row0 + wm * WM + i * 16 + quad * 4;
      #pragma unroll
      for (int j = 0; j < AJ; j++) {
        const int c = col0 + wn * WN + j * 16 + lr;
        #pragma unroll
        for (int r = 0; r < 4; r++)
          ((short*)C)[(size_t)(r0 + r) * ldc + c] = f2b(acc[i][j][r] * scale + bb[j]);
      }
    }
  } else if constexpr (MODE == 1) {
    #pragma unroll
    for (int i = 0; i < AI; i++) {
      const int r0 = row0 + wm * WM + i * 16 + quad * 4;
      float ex[AJ][4];
      #pragma unroll
      for (int j = 0; j < AJ; j++) {
        const int c = col0 + wn * WN + j * 16 + lr;
        #pragma unroll
        for (int r = 0; r < 4; r++) {
          ex[j][r] = __expf(acc[i][j][r] * scale);
          ((short*)C)[(size_t)(r0 + r) * ldc + c] = f2b(ex[j][r]);
        }
      }
      #pragma unroll
      for (int r = 0; r < 4; r++) {
        float s = 0.f;
        #pragma unroll
        for (int j = 0; j < AJ; j++) s += ex[j][r];
        s += __shfl_xor(s, 1, 64);
        s += __shfl_xor(s, 2, 64);
        s += __shfl_xor(s, 4, 64);
        s += __shfl_xor(s, 8, 64);
        if (lr == 0) atomicAdd(&aux[r0 + r], s);
      }
    }
  } else {
    #pragma unroll
    for (int i = 0; i < AI; i++) {
      const int r0 = row0 + wm * WM + i * 16 + quad * 4;
      float linv[4];
      #pragma unroll
      for (int r = 0; r < 4; r++) linv[r] = 1.0f / aux[r0 + r];
      #pragma unroll
      for (int j = 0; j < AJ; j++) {
        const int c = col0 + wn * WN + j * 16 + lr;
        #pragma unroll
        for (int r = 0; r < 4; r++)
          ((float*)C)[(size_t)(r0 + r) * ldc + c] = acc[i][j][r] * linv[r];
      }
    }
  }
}

// ---------------------------------------------------------------------------
// fp32 -> bf16 conversion for x, Wq, Wk, Wv + rowsum zeroing (one launch).
// Blocks [0, NCVT): convert (unit = 8 floats). Block NCVT: zero rowsum[4096].
// ---------------------------------------------------------------------------
#define XU  (N_TOK * DDIM / 8)      // 524288
#define WU  (DDIM * DDIM / 8)       // 131072
#define NCVT ((XU + 3 * WU) / 256)  // 3584 convert blocks
__global__ __launch_bounds__(256)
void cvt_all(const float* __restrict__ x,  const float* __restrict__ wq,
             const float* __restrict__ wk, const float* __restrict__ wv,
             short* __restrict__ xb, short* __restrict__ wqb,
             short* __restrict__ wkb, short* __restrict__ wvb,
             float* __restrict__ rowsum)
{
  if (blockIdx.x >= NCVT) {
    float4 z = {0.f, 0.f, 0.f, 0.f};
    float4* p = reinterpret_cast<float4*>(rowsum) + threadIdx.x * 4;
    p[0] = z; p[1] = z; p[2] = z; p[3] = z;
    return;
  }
  int gid = blockIdx.x * 256 + threadIdx.x;
  const float* src; short* dst; int off;
  if (gid < XU)               { src = x;  dst = xb;  off = gid; }
  else if (gid < XU + WU)     { src = wq; dst = wqb; off = gid - XU; }
  else if (gid < XU + 2 * WU) { src = wk; dst = wkb; off = gid - XU - WU; }
  else                        { src = wv; dst = wvb; off = gid - XU - 2 * WU; }
  const float4* g = reinterpret_cast<const float4*>(src) + (size_t)off * 2;
  float4 a = g[0], b = g[1];
  s16x8 o;
  o[0] = f2b(a.x); o[1] = f2b(a.y); o[2] = f2b(a.z); o[3] = f2b(a.w);
  o[4] = f2b(b.x); o[5] = f2b(b.y); o[6] = f2b(b.z); o[7] = f2b(b.w);
  reinterpret_cast<s16x8*>(dst)[off] = o;
}

// ---------------------------------------------------------------------------
// GEMM kernels (all with XCD-locality remap; GY must be 32)
// ---------------------------------------------------------------------------
__global__ __launch_bounds__(256)
void k_qkv(const short* __restrict__ xb,
           const short* __restrict__ Wqb, const short* __restrict__ Wkb,
           const short* __restrict__ Wvb,
           const float* __restrict__ bq, const float* __restrict__ bk,
           const float* __restrict__ bv,
           short* __restrict__ Qb, short* __restrict__ Kb, short* __restrict__ Vb)
{
  const short* W; const float* bias; short* out;
  if (blockIdx.z == 0)      { W = Wqb; bias = bq; out = Qb; }
  else if (blockIdx.z == 1) { W = Wkb; bias = bk; out = Kb; }
  else                      { W = Wvb; bias = bv; out = Vb; }
  int bx = blockIdx.x, by = blockIdx.y;
  xcd_remap(DDIM / 128, bx, by);
  gemm_core<128, 128, 64, 0>(xb, W, out, (float*)bias, DDIM, DDIM, DDIM, 1.0f,
                             by * 128, bx * 128);
}

__global__ __launch_bounds__(256)
void k_score(const short* __restrict__ Qb, const short* __restrict__ Kb,
             short* __restrict__ SP, float* __restrict__ rowsum)
{
  int bx = blockIdx.x, by = blockIdx.y;
  xcd_remap(N_TOK / 128, bx, by);
  gemm_core<128, 128, 64, 1>(Qb, Kb, SP, rowsum, DDIM, DDIM, N_TOK,
                             0.03125f, by * 128, bx * 128);
}

__global__ __launch_bounds__(256)
void k_pv(const short* __restrict__ SP, const short* __restrict__ Vt,
          float* __restrict__ out, const float* __restrict__ rowsum)
{
  int bx = blockIdx.x, by = blockIdx.y;
  xcd_remap(DDIM / 64, bx, by);
  gemm_core<128, 64, 128, 2>(SP, Vt, out, (float*)rowsum, N_TOK, N_TOK, DDIM,
                             1.0f, by * 128, bx * 64);
}

// ---------------------------------------------------------------------------
// V [4096,1024] -> Vt [1024,4096] (bf16)
// ---------------------------------------------------------------------------
__global__ __launch_bounds__(256)
void transpose_bf16(const short* __restrict__ in, short* __restrict__ out)
{
  __shared__ short t[64][65];
  const int j0 = blockIdx.x * 64;
  const int i0 = blockIdx.y * 64;
  const int tid = threadIdx.x;
  const int r = tid >> 2;
  const int c = (tid & 3) * 16;

  const s16x8* g = reinterpret_cast<const s16x8*>(in + (size_t)(i0 + r) * DDIM + j0 + c);
  s16x8 v0 = g[0], v1 = g[1];
  #pragma unroll
  for (int k = 0; k < 8; k++) { t[r][c + k] = v0[k]; t[r][c + 8 + k] = v1[k]; }
  __syncthreads();

  s16x8 w0, w1;
  #pragma unroll
  for (int k = 0; k < 8; k++) { w0[k] = t[c + k][r]; w1[k] = t[c + 8 + k][r]; }
  s16x8* go = reinterpret_cast<s16x8*>(out + (size_t)(j0 + r) * N_TOK + i0 + c);
  go[0] = w0; go[1] = w1;
}

// ---------------------------------------------------------------------------
extern "C" void kernel_launch(void* const* d_in, const int* in_sizes, int n_in,
                              void* d_out, int out_size, void* d_ws, size_t ws_size,
                              hipStream_t stream)
{
  const float* x  = (const float*)d_in[0];
  const float* Wq = (const float*)d_in[1];
  const float* bq = (const float*)d_in[2];
  const float* Wk = (const float*)d_in[3];
  const float* bk = (const float*)d_in[4];
  const float* Wv = (const float*)d_in[5];
  const float* bv = (const float*)d_in[6];
  float* out = (float*)d_out;

  char* ws = (char*)d_ws;
  const size_t MB = 1024 * 1024;
  short* Qb  = (short*)(ws + 0 * MB);
  short* Kb  = (short*)(ws + 8 * MB);
  short* Vb  = (short*)(ws + 16 * MB);
  short* Vt  = (short*)(ws + 24 * MB);
  short* SP  = (short*)(ws + 32 * MB);   // 32 MB (32..64MB), live from k_score on
  short* xb  = (short*)(ws + 32 * MB);   // overlaps SP (dead before k_score)
  short* Wqb = (short*)(ws + 40 * MB);
  short* Wkb = (short*)(ws + 42 * MB);
  short* Wvb = (short*)(ws + 44 * MB);
  // Past SP. ws_size >= 112MB (proven R3: split-4 partial path executed).
  float* rowsum = (float*)(ws + 64 * MB);

  dim3 b256(256);

  // fp32 -> bf16 for x and the three W's + zero rowsum (one extra block)
  cvt_all<<<dim3(NCVT + 1), b256, 0, stream>>>(
      x, Wq, Wk, Wv, xb, Wqb, Wkb, Wvb, rowsum);

  // Q/K/V = x @ W^T + b   (bf16 out), batched over z
  k_qkv<<<dim3(DDIM / 128, N_TOK / 128, 3), b256, 0, stream>>>(
      xb, Wqb, Wkb, Wvb, bq, bk, bv, Qb, Kb, Vb);

  // Vt = V^T
  transpose_bf16<<<dim3(DDIM / 64, N_TOK / 64), b256, 0, stream>>>(Vb, Vt);

  // P = exp(Q @ K^T / 32) (bf16) + rowsum atomics
  k_score<<<dim3(N_TOK / 128, N_TOK / 128), b256, 0, stream>>>(Qb, Kb, SP, rowsum);

  // O = (P @ Vt^T) / rowsum  (fp32 out), 128x64 tiles, BK=128
  k_pv<<<dim3(DDIM / 64, N_TOK / 128), b256, 0, stream>>>(SP, Vt, out, rowsum);
}

// Round 12
// 217.420 us; speedup vs baseline: 1.1517x; 1.0227x over previous
//
#include <hip/hip_runtime.h>

// N=4096, D=1024 self-attention, all GEMMs NT-form bf16 MFMA (16x16x32), fp32 acc.
// R4: BK=64 + XOR swizzle -> 0 bank conflicts (verified). R5: XCD swizzle.
// R6: k_pv BK=128. R7: softmax fused into k_score/k_pv epilogues.
// R11: rowsum @ ws+64MB zeroed by cvt_all (memset node dropped).
// R12: V-transpose fused into k_qkv epilogue (MODE 3): z==2 writes Vt directly
//   via LDS re-transpose (stride 136 -> aligned b128 reads, coalesced stores).
//   Removes transpose kernel + boundary + Vb round-trip. Dynamic LDS.
//
// ws layout:
//   Qb bf16[4096,1024] @ 0      Kb @ 8MB     Vt bf16[1024,4096] @ 24MB
//   SP bf16[4096,4096] @ 32MB   (exp'd scores; spans 32..64MB)
//   xb @ 32MB (overlaps SP; dead before k_score), Wqb @ 40MB, Wkb @ 42MB, Wvb @ 44MB
//   rowsum fp32[4096] @ 64MB    (past SP; ws_size >= 112MB proven in R3)

#define N_TOK 4096
#define DDIM  1024

typedef short s16x4 __attribute__((ext_vector_type(4)));
typedef short s16x8 __attribute__((ext_vector_type(8)));
typedef float f32x4 __attribute__((ext_vector_type(4)));

__device__ inline short f2b(float f) {
  unsigned int u = __float_as_uint(f);
  unsigned int r = (u + 0x7FFFu + ((u >> 16) & 1u)) >> 16;
  return (short)(unsigned short)r;
}

__device__ __forceinline__ void gld_lds16(const short* g, short* l) {
  __builtin_amdgcn_global_load_lds(
      (const __attribute__((address_space(1))) unsigned int*)g,
      (__attribute__((address_space(3))) unsigned int*)l, 16, 0, 0);
}

// XCD-locality remap for grids with GY=32: XCD (L%8) gets a 4-row-tile band.
__device__ __forceinline__ void xcd_remap(int gx, int& bx, int& by) {
  const int L = by * gx + bx;
  const int g = L & 7, h = L >> 3;
  by = g * 4 + (h & 3);
  bx = h >> 2;
}

// ---------------------------------------------------------------------------
// Core NT GEMM tile, bf16 in, fp32 acc, 16x16x32 MFMA. MODE epilogues:
//   0: bf16 store of scale*acc + bias                  (aux = bias)
//   1: bf16 store of exp(scale*acc) + rowsum atomics   (aux = rowsum)
//   2: fp32 store of acc / rowsum[row]                 (aux = rowsum)
//   3: bf16 TRANSPOSED store of acc + bias: C[col*ldc + row]  (aux = bias)
// Uses dynamic LDS: launch with >= lds_bytes<BM,BN,BK,MODE>().
// ---------------------------------------------------------------------------
template<int BM, int BN, int BK, int MODE>
constexpr int lds_shorts() {
  return (MODE == 3 && BN * 136 > BM * BK + BN * BK) ? BN * 136
                                                     : BM * BK + BN * BK;
}

template<int BM, int BN, int BK, int MODE>
__device__ __forceinline__ void gemm_core(
    const short* __restrict__ A, const short* __restrict__ B,
    void* __restrict__ C, float* __restrict__ aux,
    int K, int ld, int ldc, float scale, int row0, int col0)
{
  constexpr int WM = BM / 2, WN = BN / 2, AI = WM / 16, AJ = WN / 16;
  constexpr int CPR = BK / 8;
  constexpr int MASK = CPR - 1;
  constexpr int CA = BM * CPR / 256;
  constexpr int CB = BN * CPR / 256;
  constexpr int NH = BK / 32;
  extern __shared__ short smem[];
  short* As = smem;
  short* Bs = smem + BM * BK;

  const int tid  = threadIdx.x;
  const int wave = tid >> 6, lane = tid & 63;
  const int wm = wave >> 1, wn = wave & 1;
  const int quad = lane >> 4, lr = lane & 15;

  f32x4 acc[AI][AJ];
  #pragma unroll
  for (int i = 0; i < AI; i++)
    #pragma unroll
    for (int j = 0; j < AJ; j++) acc[i][j] = {0.f, 0.f, 0.f, 0.f};

  for (int kk = 0; kk < K; kk += BK) {
    __syncthreads();
    #pragma unroll
    for (int c = 0; c < CA; c++) {
      const int id = c * 256 + wave * 64 + lane;
      const int r = id / CPR, slot = id & MASK;
      const int q = slot ^ (r & MASK);
      gld_lds16(A + (size_t)(row0 + r) * ld + kk + q * 8,
                &As[(c * 256 + wave * 64) * 8]);
    }
    #pragma unroll
    for (int c = 0; c < CB; c++) {
      const int id = c * 256 + wave * 64 + lane;
      const int r = id / CPR, slot = id & MASK;
      const int q = slot ^ (r & MASK);
      gld_lds16(B + (size_t)(col0 + r) * ld + kk + q * 8,
                &Bs[(c * 256 + wave * 64) * 8]);
    }
    __syncthreads();

    #pragma unroll
    for (int h = 0; h < NH; h++) {
      s16x8 af[AI], bf[AJ];
      #pragma unroll
      for (int i = 0; i < AI; i++) {
        const int row = wm * WM + i * 16 + lr;
        const int ch = (h * 4 + quad) ^ (row & MASK);
        af[i] = *reinterpret_cast<const s16x8*>(&As[(row * CPR + ch) * 8]);
      }
      #pragma unroll
      for (int j = 0; j < AJ; j++) {
        const int row = wn * WN + j * 16 + lr;
        const int ch = (h * 4 + quad) ^ (row & MASK);
        bf[j] = *reinterpret_cast<const s16x8*>(&Bs[(row * CPR + ch) * 8]);
      }
      #pragma unroll
      for (int i = 0; i < AI; i++)
        #pragma unroll
        for (int j = 0; j < AJ; j++)
          acc[i][j] = __builtin_amdgcn_mfma_f32_16x16x32_bf16(af[i], bf[j], acc[i][j], 0, 0, 0);
    }
  }

  if constexpr (MODE == 0) {
    float bb[AJ];
    #pragma unroll
    for (int j = 0; j < AJ; j++) bb[j] = aux[col0 + wn * WN + j * 16 + lr];
    #pragma unroll
    for (int i = 0; i < AI; i++) {
      const int r0 = row0 + wm * WM + i * 16 + quad * 4;
      #pragma unroll
      for (int j = 0; j < AJ; j++) {
        const int c = col0 + wn * WN + j * 16 + lr;
        #pragma unroll
        for (int r = 0; r < 4; r++)
          ((short*)C)[(size_t)(r0 + r) * ldc + c] = f2b(acc[i][j][r] * scale + bb[j]);
      }
    }
  } else if constexpr (MODE == 1) {
    #pragma unroll
    for (int i = 0; i < AI; i++) {
      const int r0 = row0 + wm * WM + i * 16 + quad * 4;
      float ex[AJ][4];
      #pragma unroll
      for (int j = 0; j < AJ; j++) {
        const int c = col0 + wn * WN + j * 16 + lr;
        #pragma unroll
        for (int r = 0; r < 4; r++) {
          ex[j][r] = __expf(acc[i][j][r] * scale);
          ((short*)C)[(size_t)(r0 + r) * ldc + c] = f2b(ex[j][r]);
        }
      }
      #pragma unroll
      for (int r = 0; r < 4; r++) {
        float s = 0.f;
        #pragma unroll
        for (int j = 0; j < AJ; j++) s += ex[j][r];
        s += __shfl_xor(s, 1, 64);
        s += __shfl_xor(s, 2, 64);
        s += __shfl_xor(s, 4, 64);
        s += __shfl_xor(s, 8, 64);
        if (lr == 0) atomicAdd(&aux[r0 + r], s);
      }
    }
  } else if constexpr (MODE == 2) {
    #pragma unroll
    for (int i = 0; i < AI; i++) {
      const int r0 = row0 + wm * WM + i * 16 + quad * 4;
      float linv[4];
      #pragma unroll
      for (int r = 0; r < 4; r++) linv[r] = 1.0f / aux[r0 + r];
      #pragma unroll
      for (int j = 0; j < AJ; j++) {
        const int c = col0 + wn * WN + j * 16 + lr;
        #pragma unroll
        for (int r = 0; r < 4; r++)
          ((float*)C)[(size_t)(r0 + r) * ldc + c] = acc[i][j][r] * linv[r];
      }
    }
  } else {
    // MODE 3: transposed bf16 store with bias. trans[col][row], stride 136.
    float bb[AJ];
    #pragma unroll
    for (int j = 0; j < AJ; j++) bb[j] = aux[col0 + wn * WN + j * 16 + lr];
    __syncthreads();          // all waves done reading As/Bs
    short* trans = smem;      // BN x 136 shorts
    #pragma unroll
    for (int i = 0; i < AI; i++) {
      const int rl = wm * WM + i * 16 + quad * 4;   // local row base
      #pragma unroll
      for (int j = 0; j < AJ; j++) {
        const int cl = wn * WN + j * 16 + lr;       // local col
        s16x4 v;
        #pragma unroll
        for (int r = 0; r < 4; r++) v[r] = f2b(acc[i][j][r] * scale + bb[j]);
        *reinterpret_cast<s16x4*>(&trans[cl * 136 + rl]) = v;
      }
    }
    __syncthreads();
    // coalesced store: for each s, lanes cover 16 consecutive 16B spans of a row
    #pragma unroll
    for (int s = 0; s < BM * BN / 8 / 256; s++) {
      const int u = s * 256 + tid;
      const int cc = u >> (31 - __builtin_clz(BM / 8));  // u / (BM/8)
      const int seg = u & (BM / 8 - 1);
      s16x8 v = *reinterpret_cast<const s16x8*>(&trans[cc * 136 + seg * 8]);
      *reinterpret_cast<s16x8*>(
          &((short*)C)[(size_t)(col0 + cc) * ldc + row0 + seg * 8]) = v;
    }
  }
}

// ---------------------------------------------------------------------------
// fp32 -> bf16 conversion for x, Wq, Wk, Wv + rowsum zeroing (one launch).
// ---------------------------------------------------------------------------
#define XU  (N_TOK * DDIM / 8)      // 524288
#define WU  (DDIM * DDIM / 8)       // 131072
#define NCVT ((XU + 3 * WU) / 256)  // 3584 convert blocks
__global__ __launch_bounds__(256)
void cvt_all(const float* __restrict__ x,  const float* __restrict__ wq,
             const float* __restrict__ wk, const float* __restrict__ wv,
             short* __restrict__ xb, short* __restrict__ wqb,
             short* __restrict__ wkb, short* __restrict__ wvb,
             float* __restrict__ rowsum)
{
  if (blockIdx.x >= NCVT) {
    float4 z = {0.f, 0.f, 0.f, 0.f};
    float4* p = reinterpret_cast<float4*>(rowsum) + threadIdx.x * 4;
    p[0] = z; p[1] = z; p[2] = z; p[3] = z;
    return;
  }
  int gid = blockIdx.x * 256 + threadIdx.x;
  const float* src; short* dst; int off;
  if (gid < XU)               { src = x;  dst = xb;  off = gid; }
  else if (gid < XU + WU)     { src = wq; dst = wqb; off = gid - XU; }
  else if (gid < XU + 2 * WU) { src = wk; dst = wkb; off = gid - XU - WU; }
  else                        { src = wv; dst = wvb; off = gid - XU - 2 * WU; }
  const float4* g = reinterpret_cast<const float4*>(src) + (size_t)off * 2;
  float4 a = g[0], b = g[1];
  s16x8 o;
  o[0] = f2b(a.x); o[1] = f2b(a.y); o[2] = f2b(a.z); o[3] = f2b(a.w);
  o[4] = f2b(b.x); o[5] = f2b(b.y); o[6] = f2b(b.z); o[7] = f2b(b.w);
  reinterpret_cast<s16x8*>(dst)[off] = o;
}

// ---------------------------------------------------------------------------
// GEMM kernels (all with XCD-locality remap; GY must be 32)
// ---------------------------------------------------------------------------
__global__ __launch_bounds__(256)
void k_qkv(const short* __restrict__ xb,
           const short* __restrict__ Wqb, const short* __restrict__ Wkb,
           const short* __restrict__ Wvb,
           const float* __restrict__ bq, const float* __restrict__ bk,
           const float* __restrict__ bv,
           short* __restrict__ Qb, short* __restrict__ Kb, short* __restrict__ Vt)
{
  int bx = blockIdx.x, by = blockIdx.y;
  xcd_remap(DDIM / 128, bx, by);
  if (blockIdx.z == 0) {
    gemm_core<128, 128, 64, 0>(xb, Wqb, Qb, (float*)bq, DDIM, DDIM, DDIM, 1.0f,
                               by * 128, bx * 128);
  } else if (blockIdx.z == 1) {
    gemm_core<128, 128, 64, 0>(xb, Wkb, Kb, (float*)bk, DDIM, DDIM, DDIM, 1.0f,
                               by * 128, bx * 128);
  } else {
    // V: write transposed directly into Vt [1024, 4096]
    gemm_core<128, 128, 64, 3>(xb, Wvb, Vt, (float*)bv, DDIM, DDIM, N_TOK, 1.0f,
                               by * 128, bx * 128);
  }
}

__global__ __launch_bounds__(256)
void k_score(const short* __restrict__ Qb, const short* __restrict__ Kb,
             short* __restrict__ SP, float* __restrict__ rowsum)
{
  int bx = blockIdx.x, by = blockIdx.y;
  xcd_remap(N_TOK / 128, bx, by);
  gemm_core<128, 128, 64, 1>(Qb, Kb, SP, rowsum, DDIM, DDIM, N_TOK,
                             0.03125f, by * 128, bx * 128);
}

__global__ __launch_bounds__(256)
void k_pv(const short* __restrict__ SP, const short* __restrict__ Vt,
          float* __restrict__ out, const float* __restrict__ rowsum)
{
  int bx = blockIdx.x, by = blockIdx.y;
  xcd_remap(DDIM / 64, bx, by);
  gemm_core<128, 64, 128, 2>(SP, Vt, out, (float*)rowsum, N_TOK, N_TOK, DDIM,
                             1.0f, by * 128, bx * 64);
}

// ---------------------------------------------------------------------------
extern "C" void kernel_launch(void* const* d_in, const int* in_sizes, int n_in,
                              void* d_out, int out_size, void* d_ws, size_t ws_size,
                              hipStream_t stream)
{
  const float* x  = (const float*)d_in[0];
  const float* Wq = (const float*)d_in[1];
  const float* bq = (const float*)d_in[2];
  const float* Wk = (const float*)d_in[3];
  const float* bk = (const float*)d_in[4];
  const float* Wv = (const float*)d_in[5];
  const float* bv = (const float*)d_in[6];
  float* out = (float*)d_out;

  char* ws = (char*)d_ws;
  const size_t MB = 1024 * 1024;
  short* Qb  = (short*)(ws + 0 * MB);
  short* Kb  = (short*)(ws + 8 * MB);
  short* Vt  = (short*)(ws + 24 * MB);
  short* SP  = (short*)(ws + 32 * MB);   // 32 MB (32..64MB)
  short* xb  = (short*)(ws + 32 * MB);   // overlaps SP (dead before k_score)
  short* Wqb = (short*)(ws + 40 * MB);
  short* Wkb = (short*)(ws + 42 * MB);
  short* Wvb = (short*)(ws + 44 * MB);
  float* rowsum = (float*)(ws + 64 * MB); // past SP (ws >= 112MB, proven R3)

  dim3 b256(256);

  // LDS bytes per kernel (dynamic shared)
  constexpr int LDS_QKV   = lds_shorts<128, 128, 64, 3>() * 2;  // 34816
  constexpr int LDS_SCORE = lds_shorts<128, 128, 64, 1>() * 2;  // 32768
  constexpr int LDS_PV    = lds_shorts<128, 64, 128, 2>() * 2;  // 49152

  // fp32 -> bf16 for x and the three W's + zero rowsum (one extra block)
  cvt_all<<<dim3(NCVT + 1), b256, 0, stream>>>(
      x, Wq, Wk, Wv, xb, Wqb, Wkb, Wvb, rowsum);

  // Q/K = x @ W^T + b (bf16); V-slice writes Vt transposed directly
  k_qkv<<<dim3(DDIM / 128, N_TOK / 128, 3), b256, LDS_QKV, stream>>>(
      xb, Wqb, Wkb, Wvb, bq, bk, bv, Qb, Kb, Vt);

  // P = exp(Q @ K^T / 32) (bf16) + rowsum atomics
  k_score<<<dim3(N_TOK / 128, N_TOK / 128), b256, LDS_SCORE, stream>>>(
      Qb, Kb, SP, rowsum);

  // O = (P @ Vt^T) / rowsum  (fp32 out), 128x64 tiles, BK=128
  k_pv<<<dim3(DDIM / 64, N_TOK / 128), b256, LDS_PV, stream>>>(
      SP, Vt, out, rowsum);
}

// Round 13
// 213.151 us; speedup vs baseline: 1.1747x; 1.0200x over previous
//
#include <hip/hip_runtime.h>

// N=4096, D=1024 self-attention, all GEMMs NT-form bf16 MFMA (16x16x32), fp32 acc.
// R4: BK=64 + XOR swizzle -> 0 bank conflicts. R5: XCD swizzle. R6: k_pv BK=128.
// R7: softmax fused into k_score/k_pv epilogues. R11: rowsum @ ws+64MB via cvt_all.
// R12: V-transpose fused into k_qkv (MODE 3).
// R13: k_score 256x128 tile (64 MFMA per BK=64 iter -- barriers/FLOP halved;
//   grid 512 = 2/CU, launch_bounds(256,2)) + static LDS everywhere (undo R12's
//   dynamic-LDS VALU regression).
//
// ws layout:
//   Qb bf16[4096,1024] @ 0      Kb @ 8MB     Vt bf16[1024,4096] @ 24MB
//   SP bf16[4096,4096] @ 32MB   (exp'd scores; spans 32..64MB)
//   xb @ 32MB (overlaps SP; dead before k_score), Wqb @ 40MB, Wkb @ 42MB, Wvb @ 44MB
//   rowsum fp32[4096] @ 64MB    (past SP; ws_size >= 112MB proven in R3)

#define N_TOK 4096
#define DDIM  1024

typedef short s16x4 __attribute__((ext_vector_type(4)));
typedef short s16x8 __attribute__((ext_vector_type(8)));
typedef float f32x4 __attribute__((ext_vector_type(4)));

__device__ inline short f2b(float f) {
  unsigned int u = __float_as_uint(f);
  unsigned int r = (u + 0x7FFFu + ((u >> 16) & 1u)) >> 16;
  return (short)(unsigned short)r;
}

__device__ __forceinline__ void gld_lds16(const short* g, short* l) {
  __builtin_amdgcn_global_load_lds(
      (const __attribute__((address_space(1))) unsigned int*)g,
      (__attribute__((address_space(3))) unsigned int*)l, 16, 0, 0);
}

// XCD-locality remap, GY=32 grids: XCD (L%8) owns a 4-row-tile band.
__device__ __forceinline__ void xcd_remap(int gx, int& bx, int& by) {
  const int L = by * gx + bx;
  const int g = L & 7, h = L >> 3;
  by = g * 4 + (h & 3);
  bx = h >> 2;
}
// GY=16 variant (256-row tiles): XCD owns a 2-row-tile band.
__device__ __forceinline__ void xcd_remap16(int gx, int& bx, int& by) {
  const int L = by * gx + bx;
  const int g = L & 7, h = L >> 3;
  by = g * 2 + (h & 1);
  bx = h >> 1;
}

// ---------------------------------------------------------------------------
// Core NT GEMM tile, bf16 in, fp32 acc, 16x16x32 MFMA. MODE epilogues:
//   0: bf16 store of scale*acc + bias                  (aux = bias)
//   1: bf16 store of exp(scale*acc) + rowsum atomics   (aux = rowsum)
//   2: fp32 store of acc / rowsum[row]                 (aux = rowsum)
//   3: bf16 TRANSPOSED store of acc + bias: C[col*ldc + row]  (aux = bias)
// Caller provides smem of >= lds_shorts<...>() shorts (static per kernel).
// LDS chunk q of row r at slot q ^ (r & (BK/8-1)) -> conflict-free b128 reads.
// ---------------------------------------------------------------------------
template<int BM, int BN, int BK, int MODE>
constexpr int lds_shorts() {
  return (MODE == 3 && BN * 136 > BM * BK + BN * BK) ? BN * 136
                                                     : BM * BK + BN * BK;
}

template<int BM, int BN, int BK, int MODE>
__device__ __forceinline__ void gemm_core(
    const short* __restrict__ A, const short* __restrict__ B,
    void* __restrict__ C, float* __restrict__ aux, short* smem,
    int K, int ld, int ldc, float scale, int row0, int col0)
{
  constexpr int WM = BM / 2, WN = BN / 2, AI = WM / 16, AJ = WN / 16;
  constexpr int CPR = BK / 8;
  constexpr int MASK = CPR - 1;
  constexpr int CA = BM * CPR / 256;
  constexpr int CB = BN * CPR / 256;
  constexpr int NH = BK / 32;
  short* As = smem;
  short* Bs = smem + BM * BK;

  const int tid  = threadIdx.x;
  const int wave = tid >> 6, lane = tid & 63;
  const int wm = wave >> 1, wn = wave & 1;
  const int quad = lane >> 4, lr = lane & 15;

  f32x4 acc[AI][AJ];
  #pragma unroll
  for (int i = 0; i < AI; i++)
    #pragma unroll
    for (int j = 0; j < AJ; j++) acc[i][j] = {0.f, 0.f, 0.f, 0.f};

  for (int kk = 0; kk < K; kk += BK) {
    __syncthreads();
    #pragma unroll
    for (int c = 0; c < CA; c++) {
      const int id = c * 256 + wave * 64 + lane;
      const int r = id / CPR, slot = id & MASK;
      const int q = slot ^ (r & MASK);
      gld_lds16(A + (size_t)(row0 + r) * ld + kk + q * 8,
                &As[(c * 256 + wave * 64) * 8]);
    }
    #pragma unroll
    for (int c = 0; c < CB; c++) {
      const int id = c * 256 + wave * 64 + lane;
      const int r = id / CPR, slot = id & MASK;
      const int q = slot ^ (r & MASK);
      gld_lds16(B + (size_t)(col0 + r) * ld + kk + q * 8,
                &Bs[(c * 256 + wave * 64) * 8]);
    }
    __syncthreads();

    #pragma unroll
    for (int h = 0; h < NH; h++) {
      s16x8 af[AI], bf[AJ];
      #pragma unroll
      for (int i = 0; i < AI; i++) {
        const int row = wm * WM + i * 16 + lr;
        const int ch = (h * 4 + quad) ^ (row & MASK);
        af[i] = *reinterpret_cast<const s16x8*>(&As[(row * CPR + ch) * 8]);
      }
      #pragma unroll
      for (int j = 0; j < AJ; j++) {
        const int row = wn * WN + j * 16 + lr;
        const int ch = (h * 4 + quad) ^ (row & MASK);
        bf[j] = *reinterpret_cast<const s16x8*>(&Bs[(row * CPR + ch) * 8]);
      }
      #pragma unroll
      for (int i = 0; i < AI; i++)
        #pragma unroll
        for (int j = 0; j < AJ; j++)
          acc[i][j] = __builtin_amdgcn_mfma_f32_16x16x32_bf16(af[i], bf[j], acc[i][j], 0, 0, 0);
    }
  }

  if constexpr (MODE == 0) {
    float bb[AJ];
    #pragma unroll
    for (int j = 0; j < AJ; j++) bb[j] = aux[col0 + wn * WN + j * 16 + lr];
    #pragma unroll
    for (int i = 0; i < AI; i++) {
      const int r0 = row0 + wm * WM + i * 16 + quad * 4;
      #pragma unroll
      for (int j = 0; j < AJ; j++) {
        const int c = col0 + wn * WN + j * 16 + lr;
        #pragma unroll
        for (int r = 0; r < 4; r++)
          ((short*)C)[(size_t)(r0 + r) * ldc + c] = f2b(acc[i][j][r] * scale + bb[j]);
      }
    }
  } else if constexpr (MODE == 1) {
    #pragma unroll
    for (int i = 0; i < AI; i++) {
      const int r0 = row0 + wm * WM + i * 16 + quad * 4;
      float ex[AJ][4];
      #pragma unroll
      for (int j = 0; j < AJ; j++) {
        const int c = col0 + wn * WN + j * 16 + lr;
        #pragma unroll
        for (int r = 0; r < 4; r++) {
          ex[j][r] = __expf(acc[i][j][r] * scale);
          ((short*)C)[(size_t)(r0 + r) * ldc + c] = f2b(ex[j][r]);
        }
      }
      #pragma unroll
      for (int r = 0; r < 4; r++) {
        float s = 0.f;
        #pragma unroll
        for (int j = 0; j < AJ; j++) s += ex[j][r];
        s += __shfl_xor(s, 1, 64);
        s += __shfl_xor(s, 2, 64);
        s += __shfl_xor(s, 4, 64);
        s += __shfl_xor(s, 8, 64);
        if (lr == 0) atomicAdd(&aux[r0 + r], s);
      }
    }
  } else if constexpr (MODE == 2) {
    #pragma unroll
    for (int i = 0; i < AI; i++) {
      const int r0 = row0 + wm * WM + i * 16 + quad * 4;
      float linv[4];
      #pragma unroll
      for (int r = 0; r < 4; r++) linv[r] = 1.0f / aux[r0 + r];
      #pragma unroll
      for (int j = 0; j < AJ; j++) {
        const int c = col0 + wn * WN + j * 16 + lr;
        #pragma unroll
        for (int r = 0; r < 4; r++)
          ((float*)C)[(size_t)(r0 + r) * ldc + c] = acc[i][j][r] * linv[r];
      }
    }
  } else {
    // MODE 3: transposed bf16 store with bias. trans[col][row], stride 136.
    float bb[AJ];
    #pragma unroll
    for (int j = 0; j < AJ; j++) bb[j] = aux[col0 + wn * WN + j * 16 + lr];
    __syncthreads();
    short* trans = smem;      // BN x 136 shorts
    #pragma unroll
    for (int i = 0; i < AI; i++) {
      const int rl = wm * WM + i * 16 + quad * 4;
      #pragma unroll
      for (int j = 0; j < AJ; j++) {
        const int cl = wn * WN + j * 16 + lr;
        s16x4 v;
        #pragma unroll
        for (int r = 0; r < 4; r++) v[r] = f2b(acc[i][j][r] * scale + bb[j]);
        *reinterpret_cast<s16x4*>(&trans[cl * 136 + rl]) = v;
      }
    }
    __syncthreads();
    #pragma unroll
    for (int s = 0; s < BM * BN / 8 / 256; s++) {
      const int u = s * 256 + tid;
      const int cc = u >> (31 - __builtin_clz(BM / 8));
      const int seg = u & (BM / 8 - 1);
      s16x8 v = *reinterpret_cast<const s16x8*>(&trans[cc * 136 + seg * 8]);
      *reinterpret_cast<s16x8*>(
          &((short*)C)[(size_t)(col0 + cc) * ldc + row0 + seg * 8]) = v;
    }
  }
}

// ---------------------------------------------------------------------------
// fp32 -> bf16 conversion for x, Wq, Wk, Wv + rowsum zeroing (one launch).
// ---------------------------------------------------------------------------
#define XU  (N_TOK * DDIM / 8)      // 524288
#define WU  (DDIM * DDIM / 8)       // 131072
#define NCVT ((XU + 3 * WU) / 256)  // 3584 convert blocks
__global__ __launch_bounds__(256)
void cvt_all(const float* __restrict__ x,  const float* __restrict__ wq,
             const float* __restrict__ wk, const float* __restrict__ wv,
             short* __restrict__ xb, short* __restrict__ wqb,
             short* __restrict__ wkb, short* __restrict__ wvb,
             float* __restrict__ rowsum)
{
  if (blockIdx.x >= NCVT) {
    float4 z = {0.f, 0.f, 0.f, 0.f};
    float4* p = reinterpret_cast<float4*>(rowsum) + threadIdx.x * 4;
    p[0] = z; p[1] = z; p[2] = z; p[3] = z;
    return;
  }
  int gid = blockIdx.x * 256 + threadIdx.x;
  const float* src; short* dst; int off;
  if (gid < XU)               { src = x;  dst = xb;  off = gid; }
  else if (gid < XU + WU)     { src = wq; dst = wqb; off = gid - XU; }
  else if (gid < XU + 2 * WU) { src = wk; dst = wkb; off = gid - XU - WU; }
  else                        { src = wv; dst = wvb; off = gid - XU - 2 * WU; }
  const float4* g = reinterpret_cast<const float4*>(src) + (size_t)off * 2;
  float4 a = g[0], b = g[1];
  s16x8 o;
  o[0] = f2b(a.x); o[1] = f2b(a.y); o[2] = f2b(a.z); o[3] = f2b(a.w);
  o[4] = f2b(b.x); o[5] = f2b(b.y); o[6] = f2b(b.z); o[7] = f2b(b.w);
  reinterpret_cast<s16x8*>(dst)[off] = o;
}

// ---------------------------------------------------------------------------
// GEMM kernels
// ---------------------------------------------------------------------------
__global__ __launch_bounds__(256)
void k_qkv(const short* __restrict__ xb,
           const short* __restrict__ Wqb, const short* __restrict__ Wkb,
           const short* __restrict__ Wvb,
           const float* __restrict__ bq, const float* __restrict__ bk,
           const float* __restrict__ bv,
           short* __restrict__ Qb, short* __restrict__ Kb, short* __restrict__ Vt)
{
  __shared__ short smem[lds_shorts<128, 128, 64, 3>()];   // 17408 shorts
  int bx = blockIdx.x, by = blockIdx.y;
  xcd_remap(DDIM / 128, bx, by);
  if (blockIdx.z == 0) {
    gemm_core<128, 128, 64, 0>(xb, Wqb, Qb, (float*)bq, smem, DDIM, DDIM, DDIM,
                               1.0f, by * 128, bx * 128);
  } else if (blockIdx.z == 1) {
    gemm_core<128, 128, 64, 0>(xb, Wkb, Kb, (float*)bk, smem, DDIM, DDIM, DDIM,
                               1.0f, by * 128, bx * 128);
  } else {
    gemm_core<128, 128, 64, 3>(xb, Wvb, Vt, (float*)bv, smem, DDIM, DDIM, N_TOK,
                               1.0f, by * 128, bx * 128);
  }
}

// 256x128 score tile: 64 MFMA per BK=64 iter; grid 32x16 = 512 = 2/CU.
__global__ __launch_bounds__(256, 2)
void k_score(const short* __restrict__ Qb, const short* __restrict__ Kb,
             short* __restrict__ SP, float* __restrict__ rowsum)
{
  __shared__ short smem[lds_shorts<256, 128, 64, 1>()];   // 24576 shorts
  int bx = blockIdx.x, by = blockIdx.y;
  xcd_remap16(N_TOK / 128, bx, by);
  gemm_core<256, 128, 64, 1>(Qb, Kb, SP, rowsum, smem, DDIM, DDIM, N_TOK,
                             0.03125f, by * 256, bx * 128);
}

__global__ __launch_bounds__(256)
void k_pv(const short* __restrict__ SP, const short* __restrict__ Vt,
          float* __restrict__ out, const float* __restrict__ rowsum)
{
  __shared__ short smem[lds_shorts<128, 64, 128, 2>()];   // 24576 shorts
  int bx = blockIdx.x, by = blockIdx.y;
  xcd_remap(DDIM / 64, bx, by);
  gemm_core<128, 64, 128, 2>(SP, Vt, out, (float*)rowsum, smem, N_TOK, N_TOK,
                             DDIM, 1.0f, by * 128, bx * 64);
}

// ---------------------------------------------------------------------------
extern "C" void kernel_launch(void* const* d_in, const int* in_sizes, int n_in,
                              void* d_out, int out_size, void* d_ws, size_t ws_size,
                              hipStream_t stream)
{
  const float* x  = (const float*)d_in[0];
  const float* Wq = (const float*)d_in[1];
  const float* bq = (const float*)d_in[2];
  const float* Wk = (const float*)d_in[3];
  const float* bk = (const float*)d_in[4];
  const float* Wv = (const float*)d_in[5];
  const float* bv = (const float*)d_in[6];
  float* out = (float*)d_out;

  char* ws = (char*)d_ws;
  const size_t MB = 1024 * 1024;
  short* Qb  = (short*)(ws + 0 * MB);
  short* Kb  = (short*)(ws + 8 * MB);
  short* Vt  = (short*)(ws + 24 * MB);
  short* SP  = (short*)(ws + 32 * MB);   // 32 MB (32..64MB)
  short* xb  = (short*)(ws + 32 * MB);   // overlaps SP (dead before k_score)
  short* Wqb = (short*)(ws + 40 * MB);
  short* Wkb = (short*)(ws + 42 * MB);
  short* Wvb = (short*)(ws + 44 * MB);
  float* rowsum = (float*)(ws + 64 * MB); // past SP (ws >= 112MB, proven R3)

  dim3 b256(256);

  // fp32 -> bf16 for x and the three W's + zero rowsum (one extra block)
  cvt_all<<<dim3(NCVT + 1), b256, 0, stream>>>(
      x, Wq, Wk, Wv, xb, Wqb, Wkb, Wvb, rowsum);

  // Q/K = x @ W^T + b (bf16); V-slice writes Vt transposed directly
  k_qkv<<<dim3(DDIM / 128, N_TOK / 128, 3), b256, 0, stream>>>(
      xb, Wqb, Wkb, Wvb, bq, bk, bv, Qb, Kb, Vt);

  // P = exp(Q @ K^T / 32) (bf16) + rowsum atomics; 256x128 tiles
  k_score<<<dim3(N_TOK / 128, N_TOK / 256), b256, 0, stream>>>(
      Qb, Kb, SP, rowsum);

  // O = (P @ Vt^T) / rowsum  (fp32 out), 128x64 tiles, BK=128
  k_pv<<<dim3(DDIM / 64, N_TOK / 128), b256, 0, stream>>>(
      SP, Vt, out, rowsum);
}